// Round 3
// baseline (2792.696 us; speedup 1.0000x reference)
//
#include <hip/hip_runtime.h>
#include <hip/hip_fp16.h>

#define N_S 32
#define N_V 16
#define NB 8
#define HH 64
#define NIR 112
#define ROW 240  // 48 scalar + 64*3 vector channels

__device__ __forceinline__ float swishf(float x) {
  return x / (1.f + __expf(-x));
}

struct ChanDesc { int path, off, mixI, i; };

__device__ __forceinline__ void mkDesc(int t, ChanDesc& d) {
  if (t < 32) { d.path = 0; d.off = t; d.mixI = t; d.i = 0; }
  else if (t < 48) { d.path = 1; d.off = 3 * (t - 32); d.mixI = t; d.i = 0; }
  else if (t < ROW) {
    int q = t - 48, c = q / 3, i = q - 3 * c;
    d.mixI = 48 + c;
    if (c < 16) { d.path = 2; d.off = q; d.i = 0; }
    else if (c < 48) { d.path = 3; d.off = c - 16; d.i = i; }
    else { d.path = 4; d.off = 3 * (c - 48); d.i = i; }
  } else { d.path = -1; d.off = 0; d.mixI = 0; d.i = 0; }
}

__device__ __forceinline__ float evalChan(const ChanDesc& d,
                                          const float* __restrict__ srow,
                                          const float* __restrict__ vrow,
                                          float mix,
                                          float u0, float u1, float u2) {
  if (d.path == 0) return srow[d.off] * mix;                          // s passthrough
  if (d.path == 2) return vrow[d.off] * mix;                          // v passthrough
  float uo = d.i == 0 ? u0 : (d.i == 1 ? u1 : u2);
  if (d.path == 3) return srow[d.off] * uo * mix;                     // s x Y1
  float dd = vrow[d.off] * u0 + vrow[d.off + 1] * u1 + vrow[d.off + 2] * u2;
  if (d.path == 1) return dd * mix;                                   // v . u
  return 1.22474487139f * (uo * dd - vrow[d.off + d.i] * 0.33333333333f) * mix;  // v x Y2
}

// One wave (64 threads) per 64 edges.
// Phase 1: lane = edge. radial embed -> MLP (h1 via LDS transposed, h2 in regs) -> mix (fp16, LDS).
// Phase 2: lane = channel. coalesced fp32 atomics straight into d_out.
__global__ __launch_bounds__(64) void edge_kernel(
    const float* __restrict__ vec,
    const float* __restrict__ nodes_s,
    const float* __restrict__ nodes_v,
    const int* __restrict__ senders,
    const int* __restrict__ receivers,
    const float* __restrict__ W0f,
    const float* __restrict__ W1f,
    const float* __restrict__ W2f,
    float* __restrict__ out,
    int E) {
  __shared__ float hLds[HH * 64];  // h1 transposed [k][lane]; reused as fp16 mix [edge][112]
  __shared__ float uLds[64 * 3];
  __shared__ int sLds[64];
  __shared__ int rLds[64];
  __half* mixLds = reinterpret_cast<__half*>(hLds);

  const int lane = threadIdx.x;
  const int base = blockIdx.x * 64;
  const int eg = base + lane;
  const bool valid = eg < E;

  // ---- radial embedding ----
  float emb[NB];
  {
    float x = 0.f, y = 0.f, z = 0.f;
    int snd = 0, rcv = 0;
    if (valid) {
      const float* vp = vec + 3 * (size_t)eg;
      x = vp[0];
      y = vp[1];
      z = vp[2];
      snd = senders[eg];
      rcv = receivers[eg];
    }
    float r2 = x * x + y * y + z * z;
    float r = sqrtf(r2);
    float invr = 1.f / fmaxf(r, 1e-12f);
    uLds[lane * 3 + 0] = x * invr;
    uLds[lane * 3 + 1] = y * invr;
    uLds[lane * 3 + 2] = z * invr;
    sLds[lane] = snd;
    rLds[lane] = rcv;
    float env = 0.f;
    if (r < 1.f) {
      float r3 = r * r2;
      float r6 = r3 * r3;
      env = 1.f + r6 * (-28.f + (48.f - 21.f * r) * r);
    }
    float coef = 1.41421356237f * invr * env;
    if (!valid || r == 0.f) coef = 0.f;
    float ph = 3.14159265358979323846f * r;
    float s1 = sinf(ph), c1 = cosf(ph);
    float twc = 2.f * c1;
    float sp = 0.f, sc = s1;
#pragma unroll
    for (int n = 0; n < NB; ++n) {  // sin(pi*n*r) via Chebyshev recurrence
      emb[n] = coef * sc;
      float sn = twc * sc - sp;
      sp = sc;
      sc = sn;
    }
  }

  // ---- h1 = swish(emb @ W0 / sqrt(8)) -> LDS transposed [k][lane] ----
  for (int j0 = 0; j0 < HH; j0 += 8) {
    float a[8];
#pragma unroll
    for (int jj = 0; jj < 8; ++jj) a[jj] = 0.f;
#pragma unroll
    for (int k = 0; k < NB; ++k) {
      const float* wrow = W0f + k * HH + j0;  // uniform address -> s_load
      float ek = emb[k];
#pragma unroll
      for (int jj = 0; jj < 8; ++jj) a[jj] = fmaf(ek, wrow[jj], a[jj]);
    }
#pragma unroll
    for (int jj = 0; jj < 8; ++jj)
      hLds[(j0 + jj) * 64 + lane] = swishf(a[jj] * 0.35355339059f);
  }
  __syncthreads();

  // ---- h2 = swish(h1 @ W1 / 8), registers ----
  float h2[HH];
#pragma unroll
  for (int j = 0; j < HH; ++j) h2[j] = 0.f;
  for (int k = 0; k < HH; ++k) {
    float hk = hLds[k * 64 + lane];
    const float* wrow = W1f + k * HH;  // uniform -> s_load
#pragma unroll
    for (int j = 0; j < HH; ++j) h2[j] = fmaf(hk, wrow[j], h2[j]);
  }
#pragma unroll
  for (int j = 0; j < HH; ++j) h2[j] = swishf(h2[j] * 0.125f);
  __syncthreads();  // h1 consumed; LDS buffer reused for mix

  // ---- mix = h2 @ W2 / 8 -> LDS as fp16 [edge][112] ----
  for (int m0 = 0; m0 < NIR; m0 += 4) {
    float a0 = 0.f, a1 = 0.f, a2 = 0.f, a3 = 0.f;
#pragma unroll
    for (int k = 0; k < HH; ++k) {
      const float* wrow = W2f + k * NIR + m0;  // uniform -> s_load
      float hk = h2[k];
      a0 = fmaf(hk, wrow[0], a0);
      a1 = fmaf(hk, wrow[1], a1);
      a2 = fmaf(hk, wrow[2], a2);
      a3 = fmaf(hk, wrow[3], a3);
    }
    mixLds[lane * NIR + m0 + 0] = __float2half_rn(a0 * 0.125f);
    mixLds[lane * NIR + m0 + 1] = __float2half_rn(a1 * 0.125f);
    mixLds[lane * NIR + m0 + 2] = __float2half_rn(a2 * 0.125f);
    mixLds[lane * NIR + m0 + 3] = __float2half_rn(a3 * 0.125f);
  }
  __syncthreads();

  // ---- scatter: lane = output channel slot, loop over this block's edges ----
  ChanDesc d[4];
#pragma unroll
  for (int tb = 0; tb < 4; ++tb) mkDesc(tb * 64 + lane, d[tb]);

  const int cnt = min(64, E - base);
  for (int e = 0; e < cnt; ++e) {
    int snd = sLds[e], rcv = rLds[e];
    float u0 = uLds[e * 3 + 0], u1 = uLds[e * 3 + 1], u2 = uLds[e * 3 + 2];
    const float* srow = nodes_s + (size_t)snd * N_S;
    const float* vrow = nodes_v + (size_t)snd * (N_V * 3);
    const __half* mrow = mixLds + e * NIR;
    float* orow = out + (size_t)rcv * ROW;
#pragma unroll
    for (int tb = 0; tb < 4; ++tb) {
      if (d[tb].path >= 0) {
        float mix = __half2float(mrow[d[tb].mixI]);
        float val = evalChan(d[tb], srow, vrow, mix, u0, u1, u2);
        unsafeAtomicAdd(orow + tb * 64 + lane, 0.25f * val);
      }
    }
  }
}

__global__ void zero_kernel(float* __restrict__ p, int n4) {
  int i = blockIdx.x * 256 + threadIdx.x;
  if (i < n4) ((float4*)p)[i] = make_float4(0.f, 0.f, 0.f, 0.f);
}

extern "C" void kernel_launch(void* const* d_in, const int* in_sizes, int n_in,
                              void* d_out, int out_size, void* d_ws, size_t ws_size,
                              hipStream_t stream) {
  const float* vec = (const float*)d_in[0];
  const float* ns = (const float*)d_in[1];
  const float* nv = (const float*)d_in[2];
  const float* w0 = (const float*)d_in[3];
  const float* w1 = (const float*)d_in[4];
  const float* w2 = (const float*)d_in[5];
  const int* snd = (const int*)d_in[6];
  const int* rcv = (const int*)d_in[7];
  float* out = (float*)d_out;

  const int E = in_sizes[6];

  hipMemsetAsync(d_out, 0, (size_t)out_size * sizeof(float), stream);
  edge_kernel<<<(E + 63) / 64, 64, 0, stream>>>(vec, ns, nv, snd, rcv, w0, w1, w2, out, E);
}

// Round 4
// 1060.376 us; speedup vs baseline: 2.6337x; 2.6337x over previous
//
#include <hip/hip_runtime.h>
#include <hip/hip_fp16.h>

#define N_S 32
#define N_V 16
#define NB 8
#define HH 64
#define NIR 112
#define ROW 240  // 48 scalar + 64*3 vector channels

typedef __attribute__((ext_vector_type(8))) short short8;

__device__ __forceinline__ float swishf(float x) {
  return x / (1.f + __expf(-x));
}

struct ChanDesc { int path, off, mixI, i; };

__device__ __forceinline__ void mkDesc(int t, ChanDesc& d) {
  if (t < 32) { d.path = 0; d.off = t; d.mixI = t; d.i = 0; }
  else if (t < 48) { d.path = 1; d.off = 3 * (t - 32); d.mixI = t; d.i = 0; }
  else if (t < ROW) {
    int q = t - 48, c = q / 3, i = q - 3 * c;
    d.mixI = 48 + c;
    if (c < 16) { d.path = 2; d.off = q; d.i = 0; }
    else if (c < 48) { d.path = 3; d.off = c - 16; d.i = i; }
    else { d.path = 4; d.off = 3 * (c - 48); d.i = i; }
  } else { d.path = -1; d.off = 0; d.mixI = 0; d.i = 0; }
}

__device__ __forceinline__ float evalChan(const ChanDesc& d,
                                          const float* __restrict__ srow,
                                          const float* __restrict__ vrow,
                                          float mix,
                                          float u0, float u1, float u2) {
  if (d.path < 0) return 0.f;
  if (d.path == 0) return srow[d.off] * mix;                          // s passthrough
  if (d.path == 2) return vrow[d.off] * mix;                          // v passthrough
  float uo = d.i == 0 ? u0 : (d.i == 1 ? u1 : u2);
  if (d.path == 3) return srow[d.off] * uo * mix;                     // s x Y1
  float dd = vrow[d.off] * u0 + vrow[d.off + 1] * u1 + vrow[d.off + 2] * u2;
  if (d.path == 1) return dd * mix;                                   // v . u
  return 1.22474487139f * (uo * dd - vrow[d.off + d.i] * 0.33333333333f) * mix;  // v x Y2
}

__device__ __forceinline__ void radialEmb(float x, float y, float z, bool valid,
                                          float* emb, float* u0, float* u1, float* u2) {
  float r2 = x * x + y * y + z * z;
  float r = sqrtf(r2);
  float invr = 1.f / fmaxf(r, 1e-12f);
  *u0 = x * invr; *u1 = y * invr; *u2 = z * invr;
  float env = 0.f;
  if (r < 1.f) {
    float r3 = r * r2;
    float r6 = r3 * r3;
    env = 1.f + r6 * (-28.f + (48.f - 21.f * r) * r);
  }
  float coef = 1.41421356237f * invr * env;
  if (!valid || r == 0.f) coef = 0.f;
  float ph = 3.14159265358979323846f * r;
  float s1 = __sinf(ph), c1 = __cosf(ph);
  float twc = 2.f * c1;
  float sp = 0.f, sc = s1;
#pragma unroll
  for (int n = 0; n < NB; ++n) {  // sin(pi*n*r) via Chebyshev recurrence
    emb[n] = coef * sc;
    float sn = twc * sc - sp;
    sp = sc;
    sc = sn;
  }
}

// ============================ sorted-gather pipeline ============================

__global__ __launch_bounds__(256) void hist_kernel(const int* __restrict__ rcv,
                                                   int* __restrict__ hist, int E) {
  int e = blockIdx.x * 256 + threadIdx.x;
  if (e < E) atomicAdd(&hist[rcv[e]], 1);
}

__global__ __launch_bounds__(256) void scan1_kernel(const int* __restrict__ hist,
                                                    int* __restrict__ scanTmp,
                                                    int* __restrict__ bsum, int N) {
  __shared__ int sh[256];
  int t = threadIdx.x;
  int i = blockIdx.x * 256 + t;
  sh[t] = (i < N) ? hist[i] : 0;
  __syncthreads();
#pragma unroll
  for (int off = 1; off < 256; off <<= 1) {
    int x = (t >= off) ? sh[t - off] : 0;
    __syncthreads();
    sh[t] += x;
    __syncthreads();
  }
  if (i < N) scanTmp[i] = sh[t];
  if (t == 255) bsum[blockIdx.x] = sh[255];
}

__global__ __launch_bounds__(256) void scan2_kernel(int* __restrict__ bsum, int nb) {
  __shared__ int sh[256];
  int t = threadIdx.x;
  sh[t] = (t < nb) ? bsum[t] : 0;
  __syncthreads();
#pragma unroll
  for (int off = 1; off < 256; off <<= 1) {
    int x = (t >= off) ? sh[t - off] : 0;
    __syncthreads();
    sh[t] += x;
    __syncthreads();
  }
  int excl = (t == 0) ? 0 : sh[t - 1];
  if (t < nb) bsum[t] = excl;
}

__global__ __launch_bounds__(256) void scan3_kernel(const int* __restrict__ scanTmp,
                                                    const int* __restrict__ bsum,
                                                    const int* __restrict__ hist,
                                                    int* __restrict__ offs,
                                                    int* __restrict__ cursor, int N) {
  int i = blockIdx.x * 256 + threadIdx.x;
  if (i < N) {
    int incl = scanTmp[i] + bsum[blockIdx.x];
    offs[i + 1] = incl;
    cursor[i] = incl - hist[i];
    if (i == 0) offs[0] = 0;
  }
}

__global__ __launch_bounds__(256) void reorder_kernel(const int* __restrict__ rcv,
                                                      int* __restrict__ cursor,
                                                      int* __restrict__ sortedE, int E) {
  int e = blockIdx.x * 256 + threadIdx.x;
  if (e < E) {
    int pos = atomicAdd(&cursor[rcv[e]], 1);
    sortedE[pos] = e;
  }
}

// Thread = edge. Radial embed -> 8->64->64->112 MLP (weights via uniform s_load),
// write mix row as fp16.
__global__ __launch_bounds__(256) void mlp_kernel(const float* __restrict__ vec,
                                                  const float* __restrict__ W0,
                                                  const float* __restrict__ W1,
                                                  const float* __restrict__ W2,
                                                  __half* __restrict__ mixOut, int E) {
  int e = blockIdx.x * 256 + threadIdx.x;
  bool valid = e < E;
  float x = 0.f, y = 0.f, z = 0.f;
  if (valid) {
    const float* vp = vec + 3 * (size_t)e;
    x = vp[0]; y = vp[1]; z = vp[2];
  }
  float emb[NB], u0, u1, u2;
  radialEmb(x, y, z, valid, emb, &u0, &u1, &u2);

  // h2 accumulation with h1 fused (k rolled, j unrolled: constant reg indices)
  float h2[HH];
#pragma unroll
  for (int j = 0; j < HH; ++j) h2[j] = 0.f;
  for (int k = 0; k < HH; ++k) {
    float h1k = 0.f;
#pragma unroll
    for (int n = 0; n < NB; ++n) h1k = fmaf(emb[n], W0[n * HH + k], h1k);
    h1k = swishf(h1k * 0.35355339059f);
    const float* wrow = W1 + k * HH;
#pragma unroll
    for (int j = 0; j < HH; ++j) h2[j] = fmaf(h1k, wrow[j], h2[j]);
  }
#pragma unroll
  for (int j = 0; j < HH; ++j) h2[j] = swishf(h2[j] * 0.125f);

  __half* mrow = mixOut + (size_t)e * NIR;
  for (int g = 0; g < NIR / 8; ++g) {  // rolled outer, unrolled inner
    float a[8];
#pragma unroll
    for (int jj = 0; jj < 8; ++jj) a[jj] = 0.f;
#pragma unroll
    for (int k = 0; k < HH; ++k) {
      const float* wrow = W2 + k * NIR + g * 8;
      float hk = h2[k];
#pragma unroll
      for (int jj = 0; jj < 8; ++jj) a[jj] = fmaf(hk, wrow[jj], a[jj]);
    }
    short8 pk;
#pragma unroll
    for (int jj = 0; jj < 8; ++jj)
      pk[jj] = (short)__half_as_ushort(__float2half_rn(a[jj] * 0.125f));
    if (valid) *reinterpret_cast<short8*>(mrow + g * 8) = pk;
  }
}

// One wave per receiver; lane = channel slot. Register accumulation, plain stores.
__global__ __launch_bounds__(256) void gather_kernel(
    const float* __restrict__ vec,
    const float* __restrict__ nodes_s,
    const float* __restrict__ nodes_v,
    const int* __restrict__ senders,
    const int* __restrict__ offs,
    const int* __restrict__ sortedE,
    const __half* __restrict__ mix,
    float* __restrict__ out, int N) {
  int wid = blockIdx.x * 4 + (threadIdx.x >> 6);
  int lane = threadIdx.x & 63;
  if (wid >= N) return;

  ChanDesc d[4];
#pragma unroll
  for (int tb = 0; tb < 4; ++tb) mkDesc(tb * 64 + lane, d[tb]);

  float acc[4] = {0.f, 0.f, 0.f, 0.f};
  int s0 = offs[wid], s1 = offs[wid + 1];

  for (int i = s0; i < s1; ++i) {
    int e = __builtin_amdgcn_readfirstlane(sortedE[i]);
    int snd = __builtin_amdgcn_readfirstlane(senders[e]);
    const float* vp = vec + 3 * (size_t)e;
    float x = vp[0], y = vp[1], z = vp[2];
    float r = sqrtf(x * x + y * y + z * z);
    float invr = 1.f / fmaxf(r, 1e-12f);
    float u0 = x * invr, u1 = y * invr, u2 = z * invr;
    const float* srow = nodes_s + (size_t)snd * N_S;
    const float* vrow = nodes_v + (size_t)snd * (N_V * 3);
    const __half* mrow = mix + (size_t)e * NIR;
#pragma unroll
    for (int tb = 0; tb < 4; ++tb) {
      if (d[tb].path >= 0) {
        float m = __half2float(mrow[d[tb].mixI]);
        acc[tb] += evalChan(d[tb], srow, vrow, m, u0, u1, u2);
      }
    }
  }

  float* orow = out + (size_t)wid * ROW;
#pragma unroll
  for (int tb = 0; tb < 4; ++tb) {
    int t = tb * 64 + lane;
    if (t < ROW) orow[t] = 0.25f * acc[tb];
  }
}

// ============================ fallback (round-3 path) ============================

__global__ __launch_bounds__(64) void edge_kernel(
    const float* __restrict__ vec,
    const float* __restrict__ nodes_s,
    const float* __restrict__ nodes_v,
    const int* __restrict__ senders,
    const int* __restrict__ receivers,
    const float* __restrict__ W0f,
    const float* __restrict__ W1f,
    const float* __restrict__ W2f,
    float* __restrict__ out,
    int E) {
  __shared__ float hLds[HH * 64];
  __shared__ float uLds[64 * 3];
  __shared__ int sLds[64];
  __shared__ int rLds[64];
  __half* mixLds = reinterpret_cast<__half*>(hLds);

  const int lane = threadIdx.x;
  const int base = blockIdx.x * 64;
  const int eg = base + lane;
  const bool valid = eg < E;

  float emb[NB];
  {
    float x = 0.f, y = 0.f, z = 0.f;
    int snd = 0, rcv = 0;
    if (valid) {
      const float* vp = vec + 3 * (size_t)eg;
      x = vp[0]; y = vp[1]; z = vp[2];
      snd = senders[eg];
      rcv = receivers[eg];
    }
    float u0, u1, u2;
    radialEmb(x, y, z, valid, emb, &u0, &u1, &u2);
    uLds[lane * 3 + 0] = u0;
    uLds[lane * 3 + 1] = u1;
    uLds[lane * 3 + 2] = u2;
    sLds[lane] = snd;
    rLds[lane] = rcv;
  }

  for (int j0 = 0; j0 < HH; j0 += 8) {
    float a[8];
#pragma unroll
    for (int jj = 0; jj < 8; ++jj) a[jj] = 0.f;
#pragma unroll
    for (int k = 0; k < NB; ++k) {
      const float* wrow = W0f + k * HH + j0;
      float ek = emb[k];
#pragma unroll
      for (int jj = 0; jj < 8; ++jj) a[jj] = fmaf(ek, wrow[jj], a[jj]);
    }
#pragma unroll
    for (int jj = 0; jj < 8; ++jj)
      hLds[(j0 + jj) * 64 + lane] = swishf(a[jj] * 0.35355339059f);
  }
  __syncthreads();

  float h2[HH];
#pragma unroll
  for (int j = 0; j < HH; ++j) h2[j] = 0.f;
  for (int k = 0; k < HH; ++k) {
    float hk = hLds[k * 64 + lane];
    const float* wrow = W1f + k * HH;
#pragma unroll
    for (int j = 0; j < HH; ++j) h2[j] = fmaf(hk, wrow[j], h2[j]);
  }
#pragma unroll
  for (int j = 0; j < HH; ++j) h2[j] = swishf(h2[j] * 0.125f);
  __syncthreads();

  for (int m0 = 0; m0 < NIR; m0 += 4) {
    float a0 = 0.f, a1 = 0.f, a2 = 0.f, a3 = 0.f;
#pragma unroll
    for (int k = 0; k < HH; ++k) {
      const float* wrow = W2f + k * NIR + m0;
      float hk = h2[k];
      a0 = fmaf(hk, wrow[0], a0);
      a1 = fmaf(hk, wrow[1], a1);
      a2 = fmaf(hk, wrow[2], a2);
      a3 = fmaf(hk, wrow[3], a3);
    }
    mixLds[lane * NIR + m0 + 0] = __float2half_rn(a0 * 0.125f);
    mixLds[lane * NIR + m0 + 1] = __float2half_rn(a1 * 0.125f);
    mixLds[lane * NIR + m0 + 2] = __float2half_rn(a2 * 0.125f);
    mixLds[lane * NIR + m0 + 3] = __float2half_rn(a3 * 0.125f);
  }
  __syncthreads();

  ChanDesc d[4];
#pragma unroll
  for (int tb = 0; tb < 4; ++tb) mkDesc(tb * 64 + lane, d[tb]);

  const int cnt = min(64, E - base);
  for (int e = 0; e < cnt; ++e) {
    int snd = sLds[e], rcv = rLds[e];
    float u0 = uLds[e * 3 + 0], u1 = uLds[e * 3 + 1], u2 = uLds[e * 3 + 2];
    const float* srow = nodes_s + (size_t)snd * N_S;
    const float* vrow = nodes_v + (size_t)snd * (N_V * 3);
    const __half* mrow = mixLds + e * NIR;
    float* orow = out + (size_t)rcv * ROW;
#pragma unroll
    for (int tb = 0; tb < 4; ++tb) {
      if (d[tb].path >= 0) {
        float m = __half2float(mrow[d[tb].mixI]);
        float val = evalChan(d[tb], srow, vrow, m, u0, u1, u2);
        unsafeAtomicAdd(orow + tb * 64 + lane, 0.25f * val);
      }
    }
  }
}

// ===============================================================================

extern "C" void kernel_launch(void* const* d_in, const int* in_sizes, int n_in,
                              void* d_out, int out_size, void* d_ws, size_t ws_size,
                              hipStream_t stream) {
  const float* vec = (const float*)d_in[0];
  const float* ns = (const float*)d_in[1];
  const float* nv = (const float*)d_in[2];
  const float* w0 = (const float*)d_in[3];
  const float* w1 = (const float*)d_in[4];
  const float* w2 = (const float*)d_in[5];
  const int* snd = (const int*)d_in[6];
  const int* rcv = (const int*)d_in[7];
  float* out = (float*)d_out;

  const int E = in_sizes[6];
  const int N = in_sizes[1] / N_S;
  const int nb = (N + 255) / 256;
  const int eb = (E + 255) / 256;

  // workspace layout
  char* p = (char*)d_ws;
  __half* mixW = (__half*)p;      p += (size_t)E * NIR * sizeof(__half);
  int* hist = (int*)p;            p += (size_t)N * 4;
  int* scanTmp = (int*)p;         p += (size_t)N * 4;
  int* offs = (int*)p;            p += ((size_t)N + 1) * 4;
  int* cursor = (int*)p;          p += (size_t)N * 4;
  int* bsum = (int*)p;            p += 256 * 4;
  int* sortedE = (int*)p;         p += (size_t)E * 4;
  size_t need = (size_t)(p - (char*)d_ws);

  if (need <= ws_size && nb <= 256) {
    hipMemsetAsync(hist, 0, (size_t)N * 4, stream);
    hist_kernel<<<eb, 256, 0, stream>>>(rcv, hist, E);
    scan1_kernel<<<nb, 256, 0, stream>>>(hist, scanTmp, bsum, N);
    scan2_kernel<<<1, 256, 0, stream>>>(bsum, nb);
    scan3_kernel<<<nb, 256, 0, stream>>>(scanTmp, bsum, hist, offs, cursor, N);
    reorder_kernel<<<eb, 256, 0, stream>>>(rcv, cursor, sortedE, E);
    mlp_kernel<<<eb, 256, 0, stream>>>(vec, w0, w1, w2, mixW, E);
    gather_kernel<<<(N + 3) / 4, 256, 0, stream>>>(vec, ns, nv, snd, offs, sortedE, mixW, out, N);
  } else {
    hipMemsetAsync(d_out, 0, (size_t)out_size * sizeof(float), stream);
    edge_kernel<<<(E + 63) / 64, 64, 0, stream>>>(vec, ns, nv, snd, rcv, w0, w1, w2, out, E);
  }
}

// Round 5
// 630.894 us; speedup vs baseline: 4.4266x; 1.6808x over previous
//
#include <hip/hip_runtime.h>
#include <hip/hip_fp16.h>

#define N_S 32
#define N_V 16
#define NB 8
#define HH 64
#define NIR 112
#define ROW 240  // 48 scalar + 64*3 vector channels

typedef __attribute__((ext_vector_type(8))) short short8;
typedef _Float16 half8 __attribute__((ext_vector_type(8)));
typedef float f32x4 __attribute__((ext_vector_type(4)));

__device__ __forceinline__ float swishf(float x) {
  return x / (1.f + __expf(-x));
}

struct ChanDesc { int path, off, mixI, i; };

__device__ __forceinline__ void mkDesc(int t, ChanDesc& d) {
  if (t < 32) { d.path = 0; d.off = t; d.mixI = t; d.i = 0; }
  else if (t < 48) { d.path = 1; d.off = 3 * (t - 32); d.mixI = t; d.i = 0; }
  else if (t < ROW) {
    int q = t - 48, c = q / 3, i = q - 3 * c;
    d.mixI = 48 + c;
    if (c < 16) { d.path = 2; d.off = q; d.i = 0; }
    else if (c < 48) { d.path = 3; d.off = c - 16; d.i = i; }
    else { d.path = 4; d.off = 3 * (c - 48); d.i = i; }
  } else { d.path = -1; d.off = 0; d.mixI = 0; d.i = 0; }
}

__device__ __forceinline__ float evalChan(const ChanDesc& d,
                                          const float* __restrict__ srow,
                                          const float* __restrict__ vrow,
                                          float mix,
                                          float u0, float u1, float u2) {
  if (d.path < 0) return 0.f;
  if (d.path == 0) return srow[d.off] * mix;                          // s passthrough
  if (d.path == 2) return vrow[d.off] * mix;                          // v passthrough
  float uo = d.i == 0 ? u0 : (d.i == 1 ? u1 : u2);
  if (d.path == 3) return srow[d.off] * uo * mix;                     // s x Y1
  float dd = vrow[d.off] * u0 + vrow[d.off + 1] * u1 + vrow[d.off + 2] * u2;
  if (d.path == 1) return dd * mix;                                   // v . u
  return 1.22474487139f * (uo * dd - vrow[d.off + d.i] * 0.33333333333f) * mix;  // v x Y2
}

__device__ __forceinline__ void radialEmb(float x, float y, float z, bool valid,
                                          float* emb, float* u0, float* u1, float* u2) {
  float r2 = x * x + y * y + z * z;
  float r = sqrtf(r2);
  float invr = 1.f / fmaxf(r, 1e-12f);
  *u0 = x * invr; *u1 = y * invr; *u2 = z * invr;
  float env = 0.f;
  if (r < 1.f) {
    float r3 = r * r2;
    float r6 = r3 * r3;
    env = 1.f + r6 * (-28.f + (48.f - 21.f * r) * r);
  }
  float coef = 1.41421356237f * invr * env;
  if (!valid || r == 0.f) coef = 0.f;
  float ph = 3.14159265358979323846f * r;
  float s1 = __sinf(ph), c1 = __cosf(ph);
  float twc = 2.f * c1;
  float sp = 0.f, sc = s1;
#pragma unroll
  for (int n = 0; n < NB; ++n) {  // sin(pi*n*r) via Chebyshev recurrence
    emb[n] = coef * sc;
    float sn = twc * sc - sp;
    sp = sc;
    sc = sn;
  }
}

// ============================ sort (unchanged) ============================

__global__ __launch_bounds__(256) void hist_kernel(const int* __restrict__ rcv,
                                                   int* __restrict__ hist, int E) {
  int e = blockIdx.x * 256 + threadIdx.x;
  if (e < E) atomicAdd(&hist[rcv[e]], 1);
}

__global__ __launch_bounds__(256) void scan1_kernel(const int* __restrict__ hist,
                                                    int* __restrict__ scanTmp,
                                                    int* __restrict__ bsum, int N) {
  __shared__ int sh[256];
  int t = threadIdx.x;
  int i = blockIdx.x * 256 + t;
  sh[t] = (i < N) ? hist[i] : 0;
  __syncthreads();
#pragma unroll
  for (int off = 1; off < 256; off <<= 1) {
    int x = (t >= off) ? sh[t - off] : 0;
    __syncthreads();
    sh[t] += x;
    __syncthreads();
  }
  if (i < N) scanTmp[i] = sh[t];
  if (t == 255) bsum[blockIdx.x] = sh[255];
}

__global__ __launch_bounds__(256) void scan2_kernel(int* __restrict__ bsum, int nb) {
  __shared__ int sh[256];
  int t = threadIdx.x;
  sh[t] = (t < nb) ? bsum[t] : 0;
  __syncthreads();
#pragma unroll
  for (int off = 1; off < 256; off <<= 1) {
    int x = (t >= off) ? sh[t - off] : 0;
    __syncthreads();
    sh[t] += x;
    __syncthreads();
  }
  int excl = (t == 0) ? 0 : sh[t - 1];
  if (t < nb) bsum[t] = excl;
}

__global__ __launch_bounds__(256) void scan3_kernel(const int* __restrict__ scanTmp,
                                                    const int* __restrict__ bsum,
                                                    const int* __restrict__ hist,
                                                    int* __restrict__ offs,
                                                    int* __restrict__ cursor, int N) {
  int i = blockIdx.x * 256 + threadIdx.x;
  if (i < N) {
    int incl = scanTmp[i] + bsum[blockIdx.x];
    offs[i + 1] = incl;
    cursor[i] = incl - hist[i];
    if (i == 0) offs[0] = 0;
  }
}

__global__ __launch_bounds__(256) void reorder_kernel(const int* __restrict__ rcv,
                                                      int* __restrict__ cursor,
                                                      int* __restrict__ sortedE, int E) {
  int e = blockIdx.x * 256 + threadIdx.x;
  if (e < E) {
    int pos = atomicAdd(&cursor[rcv[e]], 1);
    sortedE[pos] = e;
  }
}

// ==================== weights -> fp16 transposed (scales folded) ====================

__global__ __launch_bounds__(256) void wconv2_kernel(const float* __restrict__ W1,
                                                     const float* __restrict__ W2,
                                                     _Float16* __restrict__ W1T,
                                                     _Float16* __restrict__ W2T) {
  int i = blockIdx.x * 256 + threadIdx.x;
  if (i < 4096) {
    int k = i >> 6, n = i & 63;
    W1T[n * 64 + k] = (_Float16)(W1[k * 64 + n] * 0.125f);
  } else if (i < 4096 + 7168) {
    int j = i - 4096;
    int k = j / 112, n = j - k * 112;
    W2T[n * 64 + k] = (_Float16)(W2[k * 112 + n] * 0.125f);
  }
}

// ==================== MFMA radial MLP ====================
// Block = 4 waves; each wave owns 64 edges + a private 9216-B LDS slice (no barriers).
// Layer0 (K=8) on VALU; layers 1/2 on mfma_f32_16x16x32_f16 (A[m=lane&15][k=q*8+j],
// B[k=q*8+j][n=lane&15], D col=lane&15 row=q*4+reg). Scales folded into W1T/W2T.
__global__ __launch_bounds__(256, 4) void mlp_mfma_kernel(
    const float* __restrict__ vec,
    const float* __restrict__ W0,
    const _Float16* __restrict__ W1T,   // [n=64][k=64], *0.125
    const _Float16* __restrict__ W2T,   // [n=112][k=64], *0.125
    __half* __restrict__ mixOut,        // [E][112]
    int E) {
  __shared__ __align__(16) _Float16 hbuf[4 * 64 * 72];
  const int lane = threadIdx.x & 63;
  const int wave = threadIdx.x >> 6;
  const int gbase = blockIdx.x * 256 + wave * 64;
  _Float16* hb = hbuf + wave * (64 * 72);

  const int m15 = lane & 15;
  const int q = lane >> 4;

  // ---- phase 1: lane = edge; emb -> h1 -> LDS row [edge][64ch] ----
  {
    int e = gbase + lane;
    bool valid = e < E;
    float x = 0.f, y = 0.f, z = 0.f;
    if (valid) {
      const float* vp = vec + 3 * (size_t)e;
      x = vp[0]; y = vp[1]; z = vp[2];
    }
    float emb[NB], u0, u1, u2;
    radialEmb(x, y, z, valid, emb, &u0, &u1, &u2);
    for (int kg = 0; kg < 8; ++kg) {
      half8 pk;
#pragma unroll
      for (int kk = 0; kk < 8; ++kk) {
        int k = kg * 8 + kk;
        float a = 0.f;
#pragma unroll
        for (int n = 0; n < NB; ++n) a = fmaf(emb[n], W0[n * HH + k], a);
        pk[kk] = (_Float16)swishf(a * 0.35355339059f);
      }
      *(half8*)(hb + lane * 72 + kg * 8) = pk;
    }
  }

  // ---- W1 B-fragments (held in regs, reused by all 4 M-tiles) ----
  half8 bW1[4][2];
#pragma unroll
  for (int nt = 0; nt < 4; ++nt)
#pragma unroll
    for (int q2 = 0; q2 < 2; ++q2)
      bW1[nt][q2] = *(const half8*)(W1T + (nt * 16 + m15) * 64 + q2 * 32 + q * 8);

  // ---- layer 1: per M-tile read A(h1), 8 MFMA, swish, write h2 back in place ----
#pragma unroll
  for (int t = 0; t < 4; ++t) {
    half8 a0 = *(const half8*)(hb + (t * 16 + m15) * 72 + q * 8);
    half8 a1 = *(const half8*)(hb + (t * 16 + m15) * 72 + 32 + q * 8);
#pragma unroll
    for (int nt = 0; nt < 4; ++nt) {
      f32x4 d = {0.f, 0.f, 0.f, 0.f};
      d = __builtin_amdgcn_mfma_f32_16x16x32_f16(a0, bW1[nt][0], d, 0, 0, 0);
      d = __builtin_amdgcn_mfma_f32_16x16x32_f16(a1, bW1[nt][1], d, 0, 0, 0);
#pragma unroll
      for (int r = 0; r < 4; ++r)
        hb[(t * 16 + q * 4 + r) * 72 + nt * 16 + m15] = (_Float16)swishf(d[r]);
    }
  }

  // ---- layer 2 A-fragments (all in regs so LDS slice can be reused for staging) ----
  half8 A2[4][2];
#pragma unroll
  for (int t = 0; t < 4; ++t)
#pragma unroll
    for (int q2 = 0; q2 < 2; ++q2)
      A2[t][q2] = *(const half8*)(hb + (t * 16 + m15) * 72 + q2 * 32 + q * 8);

  // ---- layer 2 in two halves: N-tiles 0..3 (64 ch) then 4..6 (48 ch) ----
  for (int hf = 0; hf < 2; ++hf) {
    const int ntCount = hf ? 3 : 4;
    for (int nl = 0; nl < ntCount; ++nl) {
      int ntg = hf * 4 + nl;
      half8 b0 = *(const half8*)(W2T + (ntg * 16 + m15) * 64 + q * 8);
      half8 b1 = *(const half8*)(W2T + (ntg * 16 + m15) * 64 + 32 + q * 8);
#pragma unroll
      for (int t = 0; t < 4; ++t) {
        f32x4 d = {0.f, 0.f, 0.f, 0.f};
        d = __builtin_amdgcn_mfma_f32_16x16x32_f16(A2[t][0], b0, d, 0, 0, 0);
        d = __builtin_amdgcn_mfma_f32_16x16x32_f16(A2[t][1], b1, d, 0, 0, 0);
#pragma unroll
        for (int r = 0; r < 4; ++r)
          hb[(t * 16 + q * 4 + r) * 72 + nl * 16 + m15] = (_Float16)d[r];
      }
    }
    // coalesced store of the staged half (full 16-B aligned runs)
    if (hf == 0) {
      for (int it = 0; it < 8; ++it) {
        int c = it * 64 + lane;
        int el = c >> 3, p = c & 7;
        int e = gbase + el;
        half8 v = *(const half8*)(hb + el * 72 + p * 8);
        if (e < E) *(half8*)((_Float16*)mixOut + (size_t)e * NIR + p * 8) = v;
      }
    } else {
      for (int it = 0; it < 6; ++it) {
        int c = it * 64 + lane;
        int el = (int)(((unsigned)c * 43691u) >> 18);  // c/6 for c<384
        int p = c - el * 6;
        int e = gbase + el;
        half8 v = *(const half8*)(hb + el * 72 + p * 8);
        if (e < E) *(half8*)((_Float16*)mixOut + (size_t)e * NIR + 64 + p * 8) = v;
      }
    }
  }
}

// ==================== gather (unchanged from round 4) ====================

__global__ __launch_bounds__(256) void gather_kernel(
    const float* __restrict__ vec,
    const float* __restrict__ nodes_s,
    const float* __restrict__ nodes_v,
    const int* __restrict__ senders,
    const int* __restrict__ offs,
    const int* __restrict__ sortedE,
    const __half* __restrict__ mix,
    float* __restrict__ out, int N) {
  int wid = blockIdx.x * 4 + (threadIdx.x >> 6);
  int lane = threadIdx.x & 63;
  if (wid >= N) return;

  ChanDesc d[4];
#pragma unroll
  for (int tb = 0; tb < 4; ++tb) mkDesc(tb * 64 + lane, d[tb]);

  float acc[4] = {0.f, 0.f, 0.f, 0.f};
  int s0 = offs[wid], s1 = offs[wid + 1];

  for (int i = s0; i < s1; ++i) {
    int e = __builtin_amdgcn_readfirstlane(sortedE[i]);
    int snd = __builtin_amdgcn_readfirstlane(senders[e]);
    const float* vp = vec + 3 * (size_t)e;
    float x = vp[0], y = vp[1], z = vp[2];
    float r = sqrtf(x * x + y * y + z * z);
    float invr = 1.f / fmaxf(r, 1e-12f);
    float u0 = x * invr, u1 = y * invr, u2 = z * invr;
    const float* srow = nodes_s + (size_t)snd * N_S;
    const float* vrow = nodes_v + (size_t)snd * (N_V * 3);
    const __half* mrow = mix + (size_t)e * NIR;
#pragma unroll
    for (int tb = 0; tb < 4; ++tb) {
      if (d[tb].path >= 0) {
        float m = __half2float(mrow[d[tb].mixI]);
        acc[tb] += evalChan(d[tb], srow, vrow, m, u0, u1, u2);
      }
    }
  }

  float* orow = out + (size_t)wid * ROW;
#pragma unroll
  for (int tb = 0; tb < 4; ++tb) {
    int t = tb * 64 + lane;
    if (t < ROW) orow[t] = 0.25f * acc[tb];
  }
}

// ============================ fallback (round-3 path) ============================

__global__ __launch_bounds__(64) void edge_kernel(
    const float* __restrict__ vec,
    const float* __restrict__ nodes_s,
    const float* __restrict__ nodes_v,
    const int* __restrict__ senders,
    const int* __restrict__ receivers,
    const float* __restrict__ W0f,
    const float* __restrict__ W1f,
    const float* __restrict__ W2f,
    float* __restrict__ out,
    int E) {
  __shared__ float hLds[HH * 64];
  __shared__ float uLds[64 * 3];
  __shared__ int sLds[64];
  __shared__ int rLds[64];
  __half* mixLds = reinterpret_cast<__half*>(hLds);

  const int lane = threadIdx.x;
  const int base = blockIdx.x * 64;
  const int eg = base + lane;
  const bool valid = eg < E;

  float emb[NB];
  {
    float x = 0.f, y = 0.f, z = 0.f;
    int snd = 0, rcv = 0;
    if (valid) {
      const float* vp = vec + 3 * (size_t)eg;
      x = vp[0]; y = vp[1]; z = vp[2];
      snd = senders[eg];
      rcv = receivers[eg];
    }
    float u0, u1, u2;
    radialEmb(x, y, z, valid, emb, &u0, &u1, &u2);
    uLds[lane * 3 + 0] = u0;
    uLds[lane * 3 + 1] = u1;
    uLds[lane * 3 + 2] = u2;
    sLds[lane] = snd;
    rLds[lane] = rcv;
  }

  for (int j0 = 0; j0 < HH; j0 += 8) {
    float a[8];
#pragma unroll
    for (int jj = 0; jj < 8; ++jj) a[jj] = 0.f;
#pragma unroll
    for (int k = 0; k < NB; ++k) {
      const float* wrow = W0f + k * HH + j0;
      float ek = emb[k];
#pragma unroll
      for (int jj = 0; jj < 8; ++jj) a[jj] = fmaf(ek, wrow[jj], a[jj]);
    }
#pragma unroll
    for (int jj = 0; jj < 8; ++jj)
      hLds[(j0 + jj) * 64 + lane] = swishf(a[jj] * 0.35355339059f);
  }
  __syncthreads();

  float h2[HH];
#pragma unroll
  for (int j = 0; j < HH; ++j) h2[j] = 0.f;
  for (int k = 0; k < HH; ++k) {
    float hk = hLds[k * 64 + lane];
    const float* wrow = W1f + k * HH;
#pragma unroll
    for (int j = 0; j < HH; ++j) h2[j] = fmaf(hk, wrow[j], h2[j]);
  }
#pragma unroll
  for (int j = 0; j < HH; ++j) h2[j] = swishf(h2[j] * 0.125f);
  __syncthreads();

  for (int m0 = 0; m0 < NIR; m0 += 4) {
    float a0 = 0.f, a1 = 0.f, a2 = 0.f, a3 = 0.f;
#pragma unroll
    for (int k = 0; k < HH; ++k) {
      const float* wrow = W2f + k * NIR + m0;
      float hk = h2[k];
      a0 = fmaf(hk, wrow[0], a0);
      a1 = fmaf(hk, wrow[1], a1);
      a2 = fmaf(hk, wrow[2], a2);
      a3 = fmaf(hk, wrow[3], a3);
    }
    mixLds[lane * NIR + m0 + 0] = __float2half_rn(a0 * 0.125f);
    mixLds[lane * NIR + m0 + 1] = __float2half_rn(a1 * 0.125f);
    mixLds[lane * NIR + m0 + 2] = __float2half_rn(a2 * 0.125f);
    mixLds[lane * NIR + m0 + 3] = __float2half_rn(a3 * 0.125f);
  }
  __syncthreads();

  ChanDesc d[4];
#pragma unroll
  for (int tb = 0; tb < 4; ++tb) mkDesc(tb * 64 + lane, d[tb]);

  const int cnt = min(64, E - base);
  for (int e = 0; e < cnt; ++e) {
    int snd = sLds[e], rcv = rLds[e];
    float u0 = uLds[e * 3 + 0], u1 = uLds[e * 3 + 1], u2 = uLds[e * 3 + 2];
    const float* srow = nodes_s + (size_t)snd * N_S;
    const float* vrow = nodes_v + (size_t)snd * (N_V * 3);
    const __half* mrow = mixLds + e * NIR;
    float* orow = out + (size_t)rcv * ROW;
#pragma unroll
    for (int tb = 0; tb < 4; ++tb) {
      if (d[tb].path >= 0) {
        float m = __half2float(mrow[d[tb].mixI]);
        float val = evalChan(d[tb], srow, vrow, m, u0, u1, u2);
        unsafeAtomicAdd(orow + tb * 64 + lane, 0.25f * val);
      }
    }
  }
}

// ===============================================================================

extern "C" void kernel_launch(void* const* d_in, const int* in_sizes, int n_in,
                              void* d_out, int out_size, void* d_ws, size_t ws_size,
                              hipStream_t stream) {
  const float* vec = (const float*)d_in[0];
  const float* ns = (const float*)d_in[1];
  const float* nv = (const float*)d_in[2];
  const float* w0 = (const float*)d_in[3];
  const float* w1 = (const float*)d_in[4];
  const float* w2 = (const float*)d_in[5];
  const int* snd = (const int*)d_in[6];
  const int* rcv = (const int*)d_in[7];
  float* out = (float*)d_out;

  const int E = in_sizes[6];
  const int N = in_sizes[1] / N_S;
  const int nb = (N + 255) / 256;
  const int eb = (E + 255) / 256;

  // workspace layout
  char* p = (char*)d_ws;
  __half* mixW = (__half*)p;      p += (size_t)E * NIR * sizeof(__half);
  int* hist = (int*)p;            p += (size_t)N * 4;
  int* scanTmp = (int*)p;         p += (size_t)N * 4;
  int* offs = (int*)p;            p += ((size_t)N + 1) * 4;
  int* cursor = (int*)p;          p += (size_t)N * 4;
  int* bsum = (int*)p;            p += 256 * 4;
  int* sortedE = (int*)p;         p += (size_t)E * 4;
  p = (char*)(((uintptr_t)p + 15) & ~(uintptr_t)15);  // align for half8
  _Float16* W1T = (_Float16*)p;   p += 4096 * sizeof(_Float16);
  _Float16* W2T = (_Float16*)p;   p += 7168 * sizeof(_Float16);
  size_t need = (size_t)(p - (char*)d_ws);

  if (need <= ws_size && nb <= 256) {
    hipMemsetAsync(hist, 0, (size_t)N * 4, stream);
    hist_kernel<<<eb, 256, 0, stream>>>(rcv, hist, E);
    scan1_kernel<<<nb, 256, 0, stream>>>(hist, scanTmp, bsum, N);
    scan2_kernel<<<1, 256, 0, stream>>>(bsum, nb);
    scan3_kernel<<<nb, 256, 0, stream>>>(scanTmp, bsum, hist, offs, cursor, N);
    reorder_kernel<<<eb, 256, 0, stream>>>(rcv, cursor, sortedE, E);
    wconv2_kernel<<<44, 256, 0, stream>>>(w1, w2, W1T, W2T);
    mlp_mfma_kernel<<<eb, 256, 0, stream>>>(vec, w0, W1T, W2T, mixW, E);
    gather_kernel<<<(N + 3) / 4, 256, 0, stream>>>(vec, ns, nv, snd, offs, sortedE, mixW, out, N);
  } else {
    hipMemsetAsync(d_out, 0, (size_t)out_size * sizeof(float), stream);
    edge_kernel<<<(E + 63) / 64, 64, 0, stream>>>(vec, ns, nv, snd, rcv, w0, w1, w2, out, E);
  }
}